// Round 1
// baseline (510.498 us; speedup 1.0000x reference)
//
#include <hip/hip_runtime.h>
#include <hip/hip_bf16.h>

#define BB 16
#define EE 128
#define MM 64
#define DQ 768
#define DK 256

// ---------------------------------------------------------------------------
// K1: Wf[d][e] = sum_k Wq[d][k] * Wk[e][k]   (Wf = Wq @ Wk^T)  [768,256]
// Folds the key projection into the query side: qt = relu(q) @ Wf replaces
// both qp = relu(q)@Wq and the 17-GFLOP kp = relu(keys)@Wk.
// ---------------------------------------------------------------------------
__global__ __launch_bounds__(256) void k_wfuse(const float* __restrict__ Wq,
                                               const float* __restrict__ Wk,
                                               float* __restrict__ Wf) {
  const int d = blockIdx.x;     // 0..767
  const int e = threadIdx.x;    // 0..255
  const float4* wq4 = (const float4*)(Wq + (size_t)d * DK);
  const float4* wk4 = (const float4*)(Wk + (size_t)e * DK);
  float ax = 0.f, ay = 0.f, az = 0.f, aw = 0.f;
#pragma unroll 8
  for (int c = 0; c < DK / 4; ++c) {
    const float4 a = wq4[c], b = wk4[c];
    ax = fmaf(a.x, b.x, ax);
    ay = fmaf(a.y, b.y, ay);
    az = fmaf(a.z, b.z, az);
    aw = fmaf(a.w, b.w, aw);
  }
  Wf[(size_t)d * DK + e] = (ax + ay) + (az + aw);
}

// ---------------------------------------------------------------------------
// K2: qt[r][e] = sum_d relu(querys[r][d]) * Wf[d][e]   r<2048, e<256, K=768
// 64x64 tile per block, 256 threads, 4x4 per thread, K-chunk 16.
// A staged transposed ([k][r]) so inner reads are two ds_read_b128.
// ---------------------------------------------------------------------------
__global__ __launch_bounds__(256) void k_qt(const float* __restrict__ querys,
                                            const float* __restrict__ Wf,
                                            float* __restrict__ qt) {
  __shared__ float As[16][68];  // [k][r], pad row to 68 floats (16B-aligned rows)
  __shared__ float Bs[16][68];  // [k][e]
  const int tid = threadIdx.x;
  const int r0 = blockIdx.x * 64;
  const int e0 = blockIdx.y * 64;
  const int ty = tid >> 4, tx = tid & 15;
  const int lr = tid >> 2;        // A staging: row 0..63
  const int lk = (tid & 3) * 4;   // A staging: k offset
  const int bk = tid >> 4;        // B staging: k row 0..15
  const int be = (tid & 15) * 4;  // B staging: e offset
  float acc[4][4] = {};
  for (int k0 = 0; k0 < DQ; k0 += 16) {
    float4 av = *(const float4*)&querys[(size_t)(r0 + lr) * DQ + k0 + lk];
    av.x = fmaxf(av.x, 0.f); av.y = fmaxf(av.y, 0.f);
    av.z = fmaxf(av.z, 0.f); av.w = fmaxf(av.w, 0.f);
    const float4 bv = *(const float4*)&Wf[(size_t)(k0 + bk) * DK + e0 + be];
    __syncthreads();  // previous tile fully consumed
    As[lk + 0][lr] = av.x; As[lk + 1][lr] = av.y;
    As[lk + 2][lr] = av.z; As[lk + 3][lr] = av.w;
    *(float4*)&Bs[bk][be] = bv;
    __syncthreads();
#pragma unroll
    for (int kk = 0; kk < 16; ++kk) {
      const float4 a4 = *(const float4*)&As[kk][ty * 4];
      const float4 b4 = *(const float4*)&Bs[kk][tx * 4];
      acc[0][0] = fmaf(a4.x, b4.x, acc[0][0]); acc[0][1] = fmaf(a4.x, b4.y, acc[0][1]);
      acc[0][2] = fmaf(a4.x, b4.z, acc[0][2]); acc[0][3] = fmaf(a4.x, b4.w, acc[0][3]);
      acc[1][0] = fmaf(a4.y, b4.x, acc[1][0]); acc[1][1] = fmaf(a4.y, b4.y, acc[1][1]);
      acc[1][2] = fmaf(a4.y, b4.z, acc[1][2]); acc[1][3] = fmaf(a4.y, b4.w, acc[1][3]);
      acc[2][0] = fmaf(a4.z, b4.x, acc[2][0]); acc[2][1] = fmaf(a4.z, b4.y, acc[2][1]);
      acc[2][2] = fmaf(a4.z, b4.z, acc[2][2]); acc[2][3] = fmaf(a4.z, b4.w, acc[2][3]);
      acc[3][0] = fmaf(a4.w, b4.x, acc[3][0]); acc[3][1] = fmaf(a4.w, b4.y, acc[3][1]);
      acc[3][2] = fmaf(a4.w, b4.z, acc[3][2]); acc[3][3] = fmaf(a4.w, b4.w, acc[3][3]);
    }
  }
#pragma unroll
  for (int i = 0; i < 4; ++i) {
    float4 o; o.x = acc[i][0]; o.y = acc[i][1]; o.z = acc[i][2]; o.w = acc[i][3];
    *(float4*)&qt[(size_t)(r0 + ty * 4 + i) * DK + e0 + tx * 4] = o;
  }
}

// ---------------------------------------------------------------------------
// K3: fused attention. One block per (b, a, q-half of 64).
//  logits[q][m] = qt[b,q,:] . relu(keys[b,a,m,:]) * scale + wm[m]  (masked)
//  out[b,a,q,:] = softmax_m(logits) @ keys[b,a]
// keys staged in LDS with 16B-chunk XOR swizzle (chunk ^= m>>3): the logits
// phase reads 8 rows at 1 KiB stride (bank-aliased without the swizzle).
// LDS = 64K (keys) + 16K (P) = exactly 80 KiB -> 2 blocks/CU.
// ---------------------------------------------------------------------------
__global__ __launch_bounds__(256) void k_attn(const float* __restrict__ keys,
                                              const float* __restrict__ qt,
                                              const float* __restrict__ wm_w,
                                              const float* __restrict__ wm_b,
                                              const int* __restrict__ masks,
                                              float* __restrict__ out) {
  __shared__ float kl[MM * DK];   // 65536 B, swizzled 16B chunks
  __shared__ float pl[64 * 64];   // 16384 B; tail 64 floats alias the mask bias
  float* biasp = pl + 64 * 64 - 64;

  const int tid = threadIdx.x;
  const int blk = blockIdx.x;      // (b*EE + a)*2 + h
  const int h = blk & 1;
  const int ba = blk >> 1;         // b*EE + a
  const int b = ba >> 7;

  const float* kb = keys + (size_t)ba * (MM * DK);

  // ---- stage keys (swizzled) ----
  for (int i = tid; i < MM * DK / 4; i += 256) {
    const int m = i >> 6, c = i & 63;
    const float4 v = ((const float4*)kb)[i];
    *(float4*)&kl[m * DK + ((c ^ (m >> 3)) << 2)] = v;
  }
  __syncthreads();

  // ---- wm[m] = relu(keys[m,:]) . Wm_w + b ; bias = mask ? wm : -1e12 ----
  {
    const int m = tid >> 2, part = tid & 3;
    const int sw = m >> 3;
    float s = 0.f;
#pragma unroll
    for (int c = part * 16; c < part * 16 + 16; ++c) {
      const float4 k4 = *(const float4*)&kl[m * DK + ((c ^ sw) << 2)];
      const float4 w4 = ((const float4*)wm_w)[c];
      s += fmaxf(k4.x, 0.f) * w4.x + fmaxf(k4.y, 0.f) * w4.y +
           fmaxf(k4.z, 0.f) * w4.z + fmaxf(k4.w, 0.f) * w4.w;
    }
    s += __shfl_xor(s, 1);
    s += __shfl_xor(s, 2);
    if (part == 0) {
      const int mk = masks[(size_t)ba * MM + m];
      biasp[m] = mk ? (s + wm_b[0]) : -1e12f;
    }
  }
  __syncthreads();

  // ---- logits: thread owns 2 q-rows x 8 m-cols ----
  const int qg = tid >> 3;   // 0..31
  const int mg = tid & 7;    // 0..7
  const int q0 = h * 64 + qg * 2;  // q row within this b
  const int m0 = mg * 8;
  const float4* qtb = (const float4*)(qt + (size_t)b * EE * DK);
  float acc[2][8] = {};
  for (int c = 0; c < 64; ++c) {
    const float4 qv0 = qtb[(q0 + 0) * 64 + c];
    const float4 qv1 = qtb[(q0 + 1) * 64 + c];
    const int cs = (c ^ mg) << 2;  // (m0+j)>>3 == mg for all j<8
#pragma unroll
    for (int j = 0; j < 8; ++j) {
      const float4 k4 = *(const float4*)&kl[(m0 + j) * DK + cs];
      const float rx = fmaxf(k4.x, 0.f), ry = fmaxf(k4.y, 0.f);
      const float rz = fmaxf(k4.z, 0.f), rw = fmaxf(k4.w, 0.f);
      acc[0][j] += qv0.x * rx + qv0.y * ry + qv0.z * rz + qv0.w * rw;
      acc[1][j] += qv1.x * rx + qv1.y * ry + qv1.z * rz + qv1.w * rw;
    }
  }

  // ---- softmax over m (8 lanes per q-row share via shfl_xor 1,2,4) ----
  const float scale = 0.03608439182435161f;  // 1/sqrt(768)
  float biasv[8];
#pragma unroll
  for (int j = 0; j < 8; ++j) biasv[j] = biasp[m0 + j];
  float p[2][8];
#pragma unroll
  for (int i = 0; i < 2; ++i) {
    float l[8];
    float mx = -3.4e38f;
#pragma unroll
    for (int j = 0; j < 8; ++j) {
      l[j] = fmaf(acc[i][j], scale, biasv[j]);
      mx = fmaxf(mx, l[j]);
    }
    mx = fmaxf(mx, __shfl_xor(mx, 1));
    mx = fmaxf(mx, __shfl_xor(mx, 2));
    mx = fmaxf(mx, __shfl_xor(mx, 4));
    float s = 0.f;
#pragma unroll
    for (int j = 0; j < 8; ++j) { p[i][j] = __expf(l[j] - mx); s += p[i][j]; }
    s += __shfl_xor(s, 1);
    s += __shfl_xor(s, 2);
    s += __shfl_xor(s, 4);
    const float inv = 1.f / s;
#pragma unroll
    for (int j = 0; j < 8; ++j) p[i][j] *= inv;
  }
  __syncthreads();  // all bias reads done; safe to overwrite pl tail
#pragma unroll
  for (int i = 0; i < 2; ++i) {
    const int q = qg * 2 + i;          // local q 0..63
    const int key = (q >> 2) & 7;      // bank-spread swizzle for writes
#pragma unroll
    for (int j = 0; j < 8; ++j) pl[q * 64 + ((m0 + j) ^ key)] = p[i][j];
  }
  __syncthreads();

  // ---- out[q][d] = sum_m P[q][m] * keys[m][d] (raw keys) ----
  const int dt = tid & 63;  // 16B chunk of the 256-wide d dim
  const int wv = tid >> 6;  // wave id 0..3
  float* ob = out + ((size_t)ba * EE + h * 64) * DK;
  for (int s = 0; s < 4; ++s) {
    const int qb = (s * 4 + wv) * 4;      // local q base (4 rows)
    const int key = (s * 4 + wv) & 7;     // matches pl write swizzle
    float4 o0 = {0.f, 0.f, 0.f, 0.f}, o1 = o0, o2 = o0, o3 = o0;
    for (int m = 0; m < MM; ++m) {
      const float4 k4 = *(const float4*)&kl[m * DK + ((dt ^ (m >> 3)) << 2)];
      const int mk = m ^ key;
      const float p0 = pl[(qb + 0) * 64 + mk];
      const float p1 = pl[(qb + 1) * 64 + mk];
      const float p2 = pl[(qb + 2) * 64 + mk];
      const float p3 = pl[(qb + 3) * 64 + mk];
      o0.x = fmaf(p0, k4.x, o0.x); o0.y = fmaf(p0, k4.y, o0.y);
      o0.z = fmaf(p0, k4.z, o0.z); o0.w = fmaf(p0, k4.w, o0.w);
      o1.x = fmaf(p1, k4.x, o1.x); o1.y = fmaf(p1, k4.y, o1.y);
      o1.z = fmaf(p1, k4.z, o1.z); o1.w = fmaf(p1, k4.w, o1.w);
      o2.x = fmaf(p2, k4.x, o2.x); o2.y = fmaf(p2, k4.y, o2.y);
      o2.z = fmaf(p2, k4.z, o2.z); o2.w = fmaf(p2, k4.w, o2.w);
      o3.x = fmaf(p3, k4.x, o3.x); o3.y = fmaf(p3, k4.y, o3.y);
      o3.z = fmaf(p3, k4.z, o3.z); o3.w = fmaf(p3, k4.w, o3.w);
    }
    *(float4*)&ob[(size_t)(qb + 0) * DK + dt * 4] = o0;
    *(float4*)&ob[(size_t)(qb + 1) * DK + dt * 4] = o1;
    *(float4*)&ob[(size_t)(qb + 2) * DK + dt * 4] = o2;
    *(float4*)&ob[(size_t)(qb + 3) * DK + dt * 4] = o3;
  }
}

// ---------------------------------------------------------------------------
extern "C" void kernel_launch(void* const* d_in, const int* in_sizes, int n_in,
                              void* d_out, int out_size, void* d_ws, size_t ws_size,
                              hipStream_t stream) {
  const float* querys = (const float*)d_in[0];  // [16,128,768]
  const float* keys   = (const float*)d_in[1];  // [16,128,64,256]
  const float* Wq     = (const float*)d_in[2];  // [768,256]
  const float* Wk     = (const float*)d_in[3];  // [256,256]
  const float* Wm_w   = (const float*)d_in[4];  // [256]
  const float* Wm_b   = (const float*)d_in[5];  // [1]
  const int*   masks  = (const int*)d_in[6];    // [16,128,64]
  float* out = (float*)d_out;                   // [16,128,128,256]

  float* Wf = (float*)d_ws;          // 768*256 f32
  float* qt = Wf + DQ * DK;          // 2048*256 f32  (total ws use ~2.75 MiB)

  k_wfuse<<<DQ, 256, 0, stream>>>(Wq, Wk, Wf);
  k_qt<<<dim3((BB * EE) / 64, DK / 64), 256, 0, stream>>>(querys, Wf, qt);
  k_attn<<<BB * EE * 2, 256, 0, stream>>>(keys, qt, Wm_w, Wm_b, masks, out);
}

// Round 2
// 179.241 us; speedup vs baseline: 2.8481x; 2.8481x over previous
//
#include <hip/hip_runtime.h>
#include <hip/hip_bf16.h>

#define BB 16
#define EE 128
#define MM 64
#define DQ 768
#define DK 256

typedef __attribute__((ext_vector_type(8))) short short8v;   // 8 bf16 = 4 VGPR
typedef __attribute__((ext_vector_type(4))) float f32x4;

#define MFMA16(a, b, c) __builtin_amdgcn_mfma_f32_16x16x32_bf16(a, b, c, 0, 0, 0)

__device__ __forceinline__ ushort f2bf(float f) {
  __hip_bfloat16 h = __float2bfloat16(f);
  return *reinterpret_cast<ushort*>(&h);
}
__device__ __forceinline__ uint pack2(float lo, float hi) {
  return (uint)f2bf(lo) | ((uint)f2bf(hi) << 16);
}

// ---------------------------------------------------------------------------
// K1: Wf = Wq @ Wk^T   [768,256]  (folds key projection into query side)
// ---------------------------------------------------------------------------
__global__ __launch_bounds__(256) void k_wfuse(const float* __restrict__ Wq,
                                               const float* __restrict__ Wk,
                                               float* __restrict__ Wf) {
  const int d = blockIdx.x;
  const int e = threadIdx.x;
  const float4* wq4 = (const float4*)(Wq + (size_t)d * DK);
  const float4* wk4 = (const float4*)(Wk + (size_t)e * DK);
  float ax = 0.f, ay = 0.f, az = 0.f, aw = 0.f;
#pragma unroll 8
  for (int c = 0; c < DK / 4; ++c) {
    const float4 a = wq4[c], b = wk4[c];
    ax = fmaf(a.x, b.x, ax);
    ay = fmaf(a.y, b.y, ay);
    az = fmaf(a.z, b.z, az);
    aw = fmaf(a.w, b.w, aw);
  }
  Wf[(size_t)d * DK + e] = (ax + ay) + (az + aw);
}

// ---------------------------------------------------------------------------
// K2: qt[r][e] = sum_d relu(querys[r][d]) * Wf[d][e], written as bf16.
// ---------------------------------------------------------------------------
__global__ __launch_bounds__(256) void k_qt(const float* __restrict__ querys,
                                            const float* __restrict__ Wf,
                                            ushort* __restrict__ qt) {
  __shared__ float As[16][68];
  __shared__ float Bs[16][68];
  const int tid = threadIdx.x;
  const int r0 = blockIdx.x * 64;
  const int e0 = blockIdx.y * 64;
  const int ty = tid >> 4, tx = tid & 15;
  const int lr = tid >> 2;
  const int lk = (tid & 3) * 4;
  const int bk = tid >> 4;
  const int be = (tid & 15) * 4;
  float acc[4][4] = {};
  for (int k0 = 0; k0 < DQ; k0 += 16) {
    float4 av = *(const float4*)&querys[(size_t)(r0 + lr) * DQ + k0 + lk];
    av.x = fmaxf(av.x, 0.f); av.y = fmaxf(av.y, 0.f);
    av.z = fmaxf(av.z, 0.f); av.w = fmaxf(av.w, 0.f);
    const float4 bv = *(const float4*)&Wf[(size_t)(k0 + bk) * DK + e0 + be];
    __syncthreads();
    As[lk + 0][lr] = av.x; As[lk + 1][lr] = av.y;
    As[lk + 2][lr] = av.z; As[lk + 3][lr] = av.w;
    *(float4*)&Bs[bk][be] = bv;
    __syncthreads();
#pragma unroll
    for (int kk = 0; kk < 16; ++kk) {
      const float4 a4 = *(const float4*)&As[kk][ty * 4];
      const float4 b4 = *(const float4*)&Bs[kk][tx * 4];
      acc[0][0] = fmaf(a4.x, b4.x, acc[0][0]); acc[0][1] = fmaf(a4.x, b4.y, acc[0][1]);
      acc[0][2] = fmaf(a4.x, b4.z, acc[0][2]); acc[0][3] = fmaf(a4.x, b4.w, acc[0][3]);
      acc[1][0] = fmaf(a4.y, b4.x, acc[1][0]); acc[1][1] = fmaf(a4.y, b4.y, acc[1][1]);
      acc[1][2] = fmaf(a4.y, b4.z, acc[1][2]); acc[1][3] = fmaf(a4.y, b4.w, acc[1][3]);
      acc[2][0] = fmaf(a4.z, b4.x, acc[2][0]); acc[2][1] = fmaf(a4.z, b4.y, acc[2][1]);
      acc[2][2] = fmaf(a4.z, b4.z, acc[2][2]); acc[2][3] = fmaf(a4.z, b4.w, acc[2][3]);
      acc[3][0] = fmaf(a4.w, b4.x, acc[3][0]); acc[3][1] = fmaf(a4.w, b4.y, acc[3][1]);
      acc[3][2] = fmaf(a4.w, b4.z, acc[3][2]); acc[3][3] = fmaf(a4.w, b4.w, acc[3][3]);
    }
  }
#pragma unroll
  for (int i = 0; i < 4; ++i) {
    ushort4 o;
    o.x = f2bf(acc[i][0]); o.y = f2bf(acc[i][1]);
    o.z = f2bf(acc[i][2]); o.w = f2bf(acc[i][3]);
    *(ushort4*)&qt[(size_t)(r0 + ty * 4 + i) * DK + e0 + tx * 4] = o;
  }
}

// ---------------------------------------------------------------------------
// K3: fused MFMA attention. One block per (b,a). 512 threads = 8 waves.
// LDS: relu_lds [64 m][256 d] bf16 (QK B-ops, swz (m&7)<<4)
//      kT_lds   [256 d][64 m] bf16 (PV B-ops, swz ((d&7)^((d>>3)&7))<<4)
//      P_lds    [128 q][64 m] bf16 (PV A-ops, swz ((q&7)^((q>>3)&7))<<4)
//      bias[64] f32 aliases P_lds rows 0-1 (dead until softmax P-writes).
// Total 80 KiB -> 2 blocks/CU.
// ---------------------------------------------------------------------------
__global__ __launch_bounds__(512, 4) void k_attn(
    const float* __restrict__ keys, const ushort* __restrict__ qt,
    const float* __restrict__ wm_w, const float* __restrict__ wm_b,
    const int* __restrict__ masks, float* __restrict__ out) {
  __shared__ ushort relu_lds[MM * DK];   // 32 KiB
  __shared__ ushort kT_lds[DK * MM];     // 32 KiB
  __shared__ ushort P_lds[EE * MM];      // 16 KiB
  float* biasf = (float*)P_lds;          // 64 f32, aliases P rows 0..1

  const int tid = threadIdx.x;
  const int w = tid >> 6;
  const int lane = tid & 63;
  const int ba = blockIdx.x;             // b*EE + a
  const int b = ba >> 7;

  // ================= stage: keys -> relu_lds (bf16) + kT_lds (bf16) + wm ===
  const float4* kb4 = (const float4*)(keys + (size_t)ba * (MM * DK));
  const float4 wv = ((const float4*)wm_w)[lane];
#pragma unroll
  for (int it = 0; it < 4; ++it) {
    const int m0 = w * 8 + it * 2;       // this wave's row pair
    const float4 va = kb4[(m0 + 0) * 64 + lane];
    const float4 vb = kb4[(m0 + 1) * 64 + lane];
    // exact f32 mention-bias partials
    float pa = fmaxf(va.x, 0.f) * wv.x + fmaxf(va.y, 0.f) * wv.y +
               fmaxf(va.z, 0.f) * wv.z + fmaxf(va.w, 0.f) * wv.w;
    float pb = fmaxf(vb.x, 0.f) * wv.x + fmaxf(vb.y, 0.f) * wv.y +
               fmaxf(vb.z, 0.f) * wv.z + fmaxf(vb.w, 0.f) * wv.w;
#pragma unroll
    for (int s = 1; s < 64; s <<= 1) {
      pa += __shfl_xor(pa, s);
      pb += __shfl_xor(pb, s);
    }
    if (lane < 2) {
      const int m = m0 + lane;
      const float s = (lane == 0) ? pa : pb;
      const int mk = masks[(size_t)ba * MM + m];
      biasf[m] = mk ? (s + wm_b[0]) : -1e12f;
    }
    // relu'd row-major bf16 (QK B-operand source)
    uint2 ra, rb;
    ra.x = pack2(fmaxf(va.x, 0.f), fmaxf(va.y, 0.f));
    ra.y = pack2(fmaxf(va.z, 0.f), fmaxf(va.w, 0.f));
    rb.x = pack2(fmaxf(vb.x, 0.f), fmaxf(vb.y, 0.f));
    rb.y = pack2(fmaxf(vb.z, 0.f), fmaxf(vb.w, 0.f));
    *(uint2*)((char*)relu_lds + (m0 + 0) * 512 + ((8 * lane) ^ (((m0 + 0) & 7) << 4))) = ra;
    *(uint2*)((char*)relu_lds + (m0 + 1) * 512 + ((8 * lane) ^ (((m0 + 1) & 7) << 4))) = rb;
    // raw transposed bf16 (PV B-operand source): kT[d][m0..m0+1]
    const float a4[4] = {va.x, va.y, va.z, va.w};
    const float b4[4] = {vb.x, vb.y, vb.z, vb.w};
#pragma unroll
    for (int j = 0; j < 4; ++j) {
      const int d = 4 * lane + j;
      const int sw = ((d & 7) ^ ((d >> 3) & 7)) << 4;
      *(uint*)((char*)kT_lds + d * 128 + ((2 * m0) ^ sw)) = pack2(a4[j], b4[j]);
    }
  }

  // preload qt A-fragments (global, L2-resident): wave w owns q rows 16w..16w+15
  const int qrow = w * 16 + (lane & 15);
  const ushort* qrowp = qt + ((size_t)b * EE + qrow) * DK + 8 * (lane >> 4);
  short8v aq[8];
#pragma unroll
  for (int ks = 0; ks < 8; ++ks) aq[ks] = *(const short8v*)(qrowp + 32 * ks);

  __syncthreads();  // staging complete

  // ================= QK^T: wave = 16 q x 64 m, K=256 ======================
  f32x4 sacc[4] = {f32x4{0.f, 0.f, 0.f, 0.f}, f32x4{0.f, 0.f, 0.f, 0.f},
                   f32x4{0.f, 0.f, 0.f, 0.f}, f32x4{0.f, 0.f, 0.f, 0.f}};
#pragma unroll
  for (int ks = 0; ks < 8; ++ks) {
#pragma unroll
    for (int mt = 0; mt < 4; ++mt) {
      const int m = mt * 16 + (lane & 15);
      const int k = ks * 32 + 8 * (lane >> 4);
      const short8v bf = *(const short8v*)((char*)relu_lds + m * 512 +
                                           ((2 * k) ^ ((m & 7) << 4)));
      sacc[mt] = MFMA16(aq[ks], bf, sacc[mt]);
    }
  }

  // ================= softmax (wave-local; rows q=16w+4*(lane>>4)+r) ========
  const float scale = 0.036084391824351615f;  // 1/sqrt(768)
  float bias_v[4];
#pragma unroll
  for (int mt = 0; mt < 4; ++mt) bias_v[mt] = biasf[mt * 16 + (lane & 15)];
  float ex[4][4], rmax[4], rsum[4];
#pragma unroll
  for (int r = 0; r < 4; ++r) rmax[r] = -3.4e38f;
#pragma unroll
  for (int mt = 0; mt < 4; ++mt)
#pragma unroll
    for (int r = 0; r < 4; ++r) {
      const float l = fmaf(sacc[mt][r], scale, bias_v[mt]);
      ex[mt][r] = l;
      rmax[r] = fmaxf(rmax[r], l);
    }
#pragma unroll
  for (int r = 0; r < 4; ++r) {
    rmax[r] = fmaxf(rmax[r], __shfl_xor(rmax[r], 1));
    rmax[r] = fmaxf(rmax[r], __shfl_xor(rmax[r], 2));
    rmax[r] = fmaxf(rmax[r], __shfl_xor(rmax[r], 4));
    rmax[r] = fmaxf(rmax[r], __shfl_xor(rmax[r], 8));
    rsum[r] = 0.f;
  }
#pragma unroll
  for (int mt = 0; mt < 4; ++mt)
#pragma unroll
    for (int r = 0; r < 4; ++r) {
      ex[mt][r] = __expf(ex[mt][r] - rmax[r]);
      rsum[r] += ex[mt][r];
    }
  float rinv[4];
#pragma unroll
  for (int r = 0; r < 4; ++r) {
    rsum[r] += __shfl_xor(rsum[r], 1);
    rsum[r] += __shfl_xor(rsum[r], 2);
    rsum[r] += __shfl_xor(rsum[r], 4);
    rsum[r] += __shfl_xor(rsum[r], 8);
    rinv[r] = 1.f / rsum[r];
  }

  __syncthreads();  // all bias reads done; P region may be overwritten

#pragma unroll
  for (int mt = 0; mt < 4; ++mt)
#pragma unroll
    for (int r = 0; r < 4; ++r) {
      const int q = w * 16 + (lane >> 4) * 4 + r;
      const int m = mt * 16 + (lane & 15);
      const int sw = ((q & 7) ^ ((q >> 3) & 7)) << 4;
      *(ushort*)((char*)P_lds + q * 128 + ((2 * m) ^ sw)) =
          f2bf(ex[mt][r] * rinv[r]);
    }
  __syncthreads();  // P complete

  // ================= PV: wave = 64 q x 64 d, K = 64 ========================
  const int qb = 64 * (w >> 2);
  const int db = 64 * (w & 3);
  short8v ap[4][2];
#pragma unroll
  for (int qt_ = 0; qt_ < 4; ++qt_)
#pragma unroll
    for (int ks = 0; ks < 2; ++ks) {
      const int q = qb + qt_ * 16 + (lane & 15);
      const int m = ks * 32 + 8 * (lane >> 4);
      const int sw = ((q & 7) ^ ((q >> 3) & 7)) << 4;
      ap[qt_][ks] = *(const short8v*)((char*)P_lds + q * 128 + ((2 * m) ^ sw));
    }
  float* ob = out + ((size_t)ba * EE) * DK;
#pragma unroll
  for (int dt = 0; dt < 4; ++dt) {
    short8v bk[2];
#pragma unroll
    for (int ks = 0; ks < 2; ++ks) {
      const int d = db + dt * 16 + (lane & 15);
      const int m = ks * 32 + 8 * (lane >> 4);
      const int sw = ((d & 7) ^ ((d >> 3) & 7)) << 4;
      bk[ks] = *(const short8v*)((char*)kT_lds + d * 128 + ((2 * m) ^ sw));
    }
#pragma unroll
    for (int qt_ = 0; qt_ < 4; ++qt_) {
      f32x4 o = {0.f, 0.f, 0.f, 0.f};
      o = MFMA16(ap[qt_][0], bk[0], o);
      o = MFMA16(ap[qt_][1], bk[1], o);
      const int q = qb + qt_ * 16 + (lane >> 4) * 4;
      float* op = ob + (size_t)q * DK + db + dt * 16 + (lane & 15);
#pragma unroll
      for (int r = 0; r < 4; ++r) op[(size_t)r * DK] = o[r];
    }
  }
}

// ---------------------------------------------------------------------------
extern "C" void kernel_launch(void* const* d_in, const int* in_sizes, int n_in,
                              void* d_out, int out_size, void* d_ws, size_t ws_size,
                              hipStream_t stream) {
  const float* querys = (const float*)d_in[0];  // [16,128,768]
  const float* keys   = (const float*)d_in[1];  // [16,128,64,256]
  const float* Wq     = (const float*)d_in[2];  // [768,256]
  const float* Wk     = (const float*)d_in[3];  // [256,256]
  const float* Wm_w   = (const float*)d_in[4];  // [256]
  const float* Wm_b   = (const float*)d_in[5];  // [1]
  const int*   masks  = (const int*)d_in[6];    // [16,128,64]
  float* out = (float*)d_out;                   // [16,128,128,256]

  float*  Wf    = (float*)d_ws;                         // 768*256 f32
  ushort* qt_bf = (ushort*)((char*)d_ws + DQ * DK * 4); // 2048*256 bf16

  k_wfuse<<<DQ, 256, 0, stream>>>(Wq, Wk, Wf);
  k_qt<<<dim3((BB * EE) / 64, DK / 64), 256, 0, stream>>>(querys, Wf, qt_bf);
  k_attn<<<BB * EE, 512, 0, stream>>>(keys, qt_bf, Wm_w, Wm_b, masks, out);
}

// Round 3
// 169.135 us; speedup vs baseline: 3.0183x; 1.0597x over previous
//
#include <hip/hip_runtime.h>
#include <hip/hip_bf16.h>

#define BB 16
#define EE 128
#define MM 64
#define DQ 768
#define DK 256

typedef __attribute__((ext_vector_type(8))) short short8v;   // 8 bf16 = 4 VGPR
typedef __attribute__((ext_vector_type(4))) float f32x4;

#define MFMA16(a, b, c) __builtin_amdgcn_mfma_f32_16x16x32_bf16(a, b, c, 0, 0, 0)

__device__ __forceinline__ ushort f2bf(float f) {
  __hip_bfloat16 h = __float2bfloat16(f);
  return *reinterpret_cast<ushort*>(&h);
}
__device__ __forceinline__ uint pack2(float lo, float hi) {
  return (uint)f2bf(lo) | ((uint)f2bf(hi) << 16);
}

// ---------------------------------------------------------------------------
// K1: WfT[e][d] = sum_k Wq[d][k] * Wk[e][k]  (= (Wq @ Wk^T)^T, bf16)
// Folds the key projection into the query side; transposed+bf16 so k_qt can
// read B-fragments as contiguous 16B chunks.
// ---------------------------------------------------------------------------
__global__ __launch_bounds__(256) void k_wfuse(const float* __restrict__ Wq,
                                               const float* __restrict__ Wk,
                                               ushort* __restrict__ wfT) {
  const int d = blockIdx.x;     // 0..767
  const int e = threadIdx.x;    // 0..255
  const float4* wq4 = (const float4*)(Wq + (size_t)d * DK);
  const float4* wk4 = (const float4*)(Wk + (size_t)e * DK);
  float ax = 0.f, ay = 0.f, az = 0.f, aw = 0.f;
#pragma unroll 8
  for (int c = 0; c < DK / 4; ++c) {
    const float4 a = wq4[c], b = wk4[c];
    ax = fmaf(a.x, b.x, ax);
    ay = fmaf(a.y, b.y, ay);
    az = fmaf(a.z, b.z, az);
    aw = fmaf(a.w, b.w, aw);
  }
  wfT[(size_t)e * DQ + d] = f2bf((ax + ay) + (az + aw));
}

// ---------------------------------------------------------------------------
// K2: qt[r][e] = sum_d relu(querys[r][d]) * WfT[e][d], bf16 MFMA, no LDS.
// Block = 128 thr (2 waves); wave = 16 rows x 64 e. Grid (64, 4) = 256 blocks.
// A-frags: f32 global loads + in-register relu/pack. B-frags: b128 from WfT.
// ---------------------------------------------------------------------------
__global__ __launch_bounds__(128) void k_qt(const float* __restrict__ querys,
                                            const ushort* __restrict__ wfT,
                                            ushort* __restrict__ qt) {
  const int tid = threadIdx.x;
  const int w = tid >> 6;
  const int lane = tid & 63;
  const int lo = lane & 15, hi = lane >> 4;
  const int r0 = blockIdx.x * 32 + w * 16;
  const int e0 = blockIdx.y * 64;
  const float* qrow = querys + (size_t)(r0 + lo) * DQ;
  f32x4 acc[4] = {f32x4{0.f, 0.f, 0.f, 0.f}, f32x4{0.f, 0.f, 0.f, 0.f},
                  f32x4{0.f, 0.f, 0.f, 0.f}, f32x4{0.f, 0.f, 0.f, 0.f}};
#pragma unroll
  for (int kc = 0; kc < DQ; kc += 32) {
    const int k = kc + 8 * hi;
    const float4 a0 = *(const float4*)&qrow[k];
    const float4 a1 = *(const float4*)&qrow[k + 4];
    union { short8v v; uint u[4]; } af;
    af.u[0] = pack2(fmaxf(a0.x, 0.f), fmaxf(a0.y, 0.f));
    af.u[1] = pack2(fmaxf(a0.z, 0.f), fmaxf(a0.w, 0.f));
    af.u[2] = pack2(fmaxf(a1.x, 0.f), fmaxf(a1.y, 0.f));
    af.u[3] = pack2(fmaxf(a1.z, 0.f), fmaxf(a1.w, 0.f));
#pragma unroll
    for (int et = 0; et < 4; ++et) {
      const short8v bf = *(const short8v*)&wfT[(size_t)(e0 + et * 16 + lo) * DQ + k];
      acc[et] = MFMA16(af.v, bf, acc[et]);
    }
  }
#pragma unroll
  for (int et = 0; et < 4; ++et)
#pragma unroll
    for (int r = 0; r < 4; ++r)
      qt[(size_t)(r0 + hi * 4 + r) * DK + e0 + et * 16 + lo] = f2bf(acc[et][r]);
}

// ---------------------------------------------------------------------------
// K3: fused MFMA attention. One block per (b,a). 512 threads = 8 waves.
// LDS: relu_lds [64 m][256 d] bf16 (QK B-ops, swz (m&7)<<4)
//      kT_lds   [256 d][64 m] bf16 (PV A-ops, swz ((d&7)^((d>>3)&7))<<4)
//      P_lds    [128 q][64 m] bf16 (PV B-ops, swz ((q&7)^((q>>3)&7))<<4)
//      bias[64] f32 aliases P_lds rows 0-1 (dead until softmax P-writes).
// PV computes D[d][q] (operands swapped) so each lane stores float4 of
// 4 consecutive d — 16 dwordx4 stores/lane instead of 64 scalar dwords.
// ---------------------------------------------------------------------------
__global__ __launch_bounds__(512, 4) void k_attn(
    const float* __restrict__ keys, const ushort* __restrict__ qt,
    const float* __restrict__ wm_w, const float* __restrict__ wm_b,
    const int* __restrict__ masks, float* __restrict__ out) {
  __shared__ ushort relu_lds[MM * DK];   // 32 KiB
  __shared__ ushort kT_lds[DK * MM];     // 32 KiB
  __shared__ ushort P_lds[EE * MM];      // 16 KiB
  float* biasf = (float*)P_lds;          // 64 f32, aliases P rows 0..1

  const int tid = threadIdx.x;
  const int w = tid >> 6;
  const int lane = tid & 63;
  const int ba = blockIdx.x;             // b*EE + a
  const int b = ba >> 7;

  // ================= stage: keys -> relu_lds (bf16) + kT_lds (bf16) + wm ===
  const float4* kb4 = (const float4*)(keys + (size_t)ba * (MM * DK));
  const float4 wv = ((const float4*)wm_w)[lane];
#pragma unroll
  for (int it = 0; it < 4; ++it) {
    const int m0 = w * 8 + it * 2;       // this wave's row pair
    const float4 va = kb4[(m0 + 0) * 64 + lane];
    const float4 vb = kb4[(m0 + 1) * 64 + lane];
    // exact f32 mention-bias partials
    float pa = fmaxf(va.x, 0.f) * wv.x + fmaxf(va.y, 0.f) * wv.y +
               fmaxf(va.z, 0.f) * wv.z + fmaxf(va.w, 0.f) * wv.w;
    float pb = fmaxf(vb.x, 0.f) * wv.x + fmaxf(vb.y, 0.f) * wv.y +
               fmaxf(vb.z, 0.f) * wv.z + fmaxf(vb.w, 0.f) * wv.w;
#pragma unroll
    for (int s = 1; s < 64; s <<= 1) {
      pa += __shfl_xor(pa, s);
      pb += __shfl_xor(pb, s);
    }
    if (lane < 2) {
      const int m = m0 + lane;
      const float s = (lane == 0) ? pa : pb;
      const int mk = masks[(size_t)ba * MM + m];
      biasf[m] = mk ? (s + wm_b[0]) : -1e12f;
    }
    // relu'd row-major bf16 (QK B-operand source)
    uint2 ra, rb;
    ra.x = pack2(fmaxf(va.x, 0.f), fmaxf(va.y, 0.f));
    ra.y = pack2(fmaxf(va.z, 0.f), fmaxf(va.w, 0.f));
    rb.x = pack2(fmaxf(vb.x, 0.f), fmaxf(vb.y, 0.f));
    rb.y = pack2(fmaxf(vb.z, 0.f), fmaxf(vb.w, 0.f));
    *(uint2*)((char*)relu_lds + (m0 + 0) * 512 + ((8 * lane) ^ (((m0 + 0) & 7) << 4))) = ra;
    *(uint2*)((char*)relu_lds + (m0 + 1) * 512 + ((8 * lane) ^ (((m0 + 1) & 7) << 4))) = rb;
    // raw transposed bf16 (PV A-operand source): kT[d][m0..m0+1]
    const float a4[4] = {va.x, va.y, va.z, va.w};
    const float b4[4] = {vb.x, vb.y, vb.z, vb.w};
#pragma unroll
    for (int j = 0; j < 4; ++j) {
      const int d = 4 * lane + j;
      const int sw = ((d & 7) ^ ((d >> 3) & 7)) << 4;
      *(uint*)((char*)kT_lds + d * 128 + ((2 * m0) ^ sw)) = pack2(a4[j], b4[j]);
    }
  }

  // preload qt A-fragments (global, L2-resident): wave w owns q rows 16w..16w+15
  const int qrow = w * 16 + (lane & 15);
  const ushort* qrowp = qt + ((size_t)b * EE + qrow) * DK + 8 * (lane >> 4);
  short8v aq[8];
#pragma unroll
  for (int ks = 0; ks < 8; ++ks) aq[ks] = *(const short8v*)(qrowp + 32 * ks);

  __syncthreads();  // staging complete

  // ================= QK^T: wave = 16 q x 64 m, K=256 ======================
  f32x4 sacc[4] = {f32x4{0.f, 0.f, 0.f, 0.f}, f32x4{0.f, 0.f, 0.f, 0.f},
                   f32x4{0.f, 0.f, 0.f, 0.f}, f32x4{0.f, 0.f, 0.f, 0.f}};
#pragma unroll
  for (int ks = 0; ks < 8; ++ks) {
#pragma unroll
    for (int mt = 0; mt < 4; ++mt) {
      const int m = mt * 16 + (lane & 15);
      const int k = ks * 32 + 8 * (lane >> 4);
      const short8v bf = *(const short8v*)((char*)relu_lds + m * 512 +
                                           ((2 * k) ^ ((m & 7) << 4)));
      sacc[mt] = MFMA16(aq[ks], bf, sacc[mt]);
    }
  }

  // ================= softmax (wave-local; rows q=16w+4*(lane>>4)+r) ========
  const float scale = 0.036084391824351615f;  // 1/sqrt(768)
  float bias_v[4];
#pragma unroll
  for (int mt = 0; mt < 4; ++mt) bias_v[mt] = biasf[mt * 16 + (lane & 15)];
  float ex[4][4], rmax[4], rsum[4];
#pragma unroll
  for (int r = 0; r < 4; ++r) rmax[r] = -3.4e38f;
#pragma unroll
  for (int mt = 0; mt < 4; ++mt)
#pragma unroll
    for (int r = 0; r < 4; ++r) {
      const float l = fmaf(sacc[mt][r], scale, bias_v[mt]);
      ex[mt][r] = l;
      rmax[r] = fmaxf(rmax[r], l);
    }
#pragma unroll
  for (int r = 0; r < 4; ++r) {
    rmax[r] = fmaxf(rmax[r], __shfl_xor(rmax[r], 1));
    rmax[r] = fmaxf(rmax[r], __shfl_xor(rmax[r], 2));
    rmax[r] = fmaxf(rmax[r], __shfl_xor(rmax[r], 4));
    rmax[r] = fmaxf(rmax[r], __shfl_xor(rmax[r], 8));
    rsum[r] = 0.f;
  }
#pragma unroll
  for (int mt = 0; mt < 4; ++mt)
#pragma unroll
    for (int r = 0; r < 4; ++r) {
      ex[mt][r] = __expf(ex[mt][r] - rmax[r]);
      rsum[r] += ex[mt][r];
    }
  float rinv[4];
#pragma unroll
  for (int r = 0; r < 4; ++r) {
    rsum[r] += __shfl_xor(rsum[r], 1);
    rsum[r] += __shfl_xor(rsum[r], 2);
    rsum[r] += __shfl_xor(rsum[r], 4);
    rsum[r] += __shfl_xor(rsum[r], 8);
    rinv[r] = 1.f / rsum[r];
  }

  __syncthreads();  // all bias reads done; P region may be overwritten

#pragma unroll
  for (int mt = 0; mt < 4; ++mt)
#pragma unroll
    for (int r = 0; r < 4; ++r) {
      const int q = w * 16 + (lane >> 4) * 4 + r;
      const int m = mt * 16 + (lane & 15);
      const int sw = ((q & 7) ^ ((q >> 3) & 7)) << 4;
      *(ushort*)((char*)P_lds + q * 128 + ((2 * m) ^ sw)) =
          f2bf(ex[mt][r] * rinv[r]);
    }
  __syncthreads();  // P complete

  // ================= PV (swapped): D[d][q], wave = 64 q x 64 d, K = 64 =====
  const int qb = 64 * (w >> 2);
  const int db = 64 * (w & 3);
  short8v ap[4][2];
#pragma unroll
  for (int qt_ = 0; qt_ < 4; ++qt_)
#pragma unroll
    for (int ks = 0; ks < 2; ++ks) {
      const int q = qb + qt_ * 16 + (lane & 15);
      const int m = ks * 32 + 8 * (lane >> 4);
      const int sw = ((q & 7) ^ ((q >> 3) & 7)) << 4;
      ap[qt_][ks] = *(const short8v*)((char*)P_lds + q * 128 + ((2 * m) ^ sw));
    }
  float* ob = out + ((size_t)ba * EE) * DK;
#pragma unroll
  for (int dt = 0; dt < 4; ++dt) {
    short8v bk[2];
#pragma unroll
    for (int ks = 0; ks < 2; ++ks) {
      const int d = db + dt * 16 + (lane & 15);
      const int m = ks * 32 + 8 * (lane >> 4);
      const int sw = ((d & 7) ^ ((d >> 3) & 7)) << 4;
      bk[ks] = *(const short8v*)((char*)kT_lds + d * 128 + ((2 * m) ^ sw));
    }
#pragma unroll
    for (int qt_ = 0; qt_ < 4; ++qt_) {
      f32x4 o = {0.f, 0.f, 0.f, 0.f};
      o = MFMA16(bk[0], ap[qt_][0], o);   // A = kT (rows=d), B = P (cols=q)
      o = MFMA16(bk[1], ap[qt_][1], o);
      const int q = qb + qt_ * 16 + (lane & 15);
      const int d = db + dt * 16 + ((lane >> 4) << 2);
      float4 ov;
      ov.x = o[0]; ov.y = o[1]; ov.z = o[2]; ov.w = o[3];
      *(float4*)&ob[(size_t)q * DK + d] = ov;   // 4 consecutive d, one q
    }
  }
}

// ---------------------------------------------------------------------------
extern "C" void kernel_launch(void* const* d_in, const int* in_sizes, int n_in,
                              void* d_out, int out_size, void* d_ws, size_t ws_size,
                              hipStream_t stream) {
  const float* querys = (const float*)d_in[0];  // [16,128,768]
  const float* keys   = (const float*)d_in[1];  // [16,128,64,256]
  const float* Wq     = (const float*)d_in[2];  // [768,256]
  const float* Wk     = (const float*)d_in[3];  // [256,256]
  const float* Wm_w   = (const float*)d_in[4];  // [256]
  const float* Wm_b   = (const float*)d_in[5];  // [1]
  const int*   masks  = (const int*)d_in[6];    // [16,128,64]
  float* out = (float*)d_out;                   // [16,128,128,256]

  ushort* wfT   = (ushort*)d_ws;                          // 256*768 bf16
  ushort* qt_bf = (ushort*)((char*)d_ws + DK * DQ * 2);   // 2048*256 bf16

  k_wfuse<<<DQ, 256, 0, stream>>>(Wq, Wk, wfT);
  k_qt<<<dim3((BB * EE) / 32, DK / 64), 128, 0, stream>>>(querys, wfT, qt_bf);
  k_attn<<<BB * EE, 512, 0, stream>>>(keys, qt_bf, Wm_w, Wm_b, masks, out);
}